// Round 15
// baseline (98.514 us; speedup 1.0000x reference)
//
#include <hip/hip_runtime.h>

#define T_LEN 50

typedef __fp16 fp16x8 __attribute__((ext_vector_type(8)));
typedef float f32x16 __attribute__((ext_vector_type(16)));
typedef unsigned int uint4v __attribute__((ext_vector_type(4)));

__device__ __forceinline__ float EXP2(float x){ return __builtin_amdgcn_exp2f(x); }
__device__ __forceinline__ float RCP(float x){ return __builtin_amdgcn_rcpf(x); }
__device__ __forceinline__ unsigned PKU(float a, float b){
    return __builtin_bit_cast(unsigned, __builtin_amdgcn_cvt_pkrtz(a, b));
}
// v_permlane32_swap_b32: swaps a's high 32 lanes with b's low 32 lanes.
// After: a = [a.low | b.low], b = [a.high | b.high]. Pure VALU (no LDS).
__device__ __forceinline__ void plswapf(float& a, float& b){
    asm volatile("v_permlane32_swap_b32 %0, %1" : "+v"(a), "+v"(b));
}
__device__ __forceinline__ void plswapu(unsigned& a, unsigned& b){
    asm volatile("v_permlane32_swap_b32 %0, %1" : "+v"(a), "+v"(b));
}

// LSTM pointwise stage for one (layer, unit, element). Gates pre-scaled:
// i,f,o by S1=-log2e; g by S2=-2log2e (folded into weights+bias).
__device__ __forceinline__ void act(float gi, float gf, float gg, float go,
                                    float& c, float& h){
    const float S2 = -2.8853900817779268f;
    const float p = EXP2(gi);
    const float r = EXP2(gf);
    const float q = EXP2(gg);
    const float s = EXP2(go);
    const float A  = 1.0f + r;
    const float BC = (1.0f + p) * (1.0f + q);
    const float num = fmaf(c, BC, (1.0f - q) * A);
    c = num * RCP(A * BC);
    const float u = EXP2(fminf(c * S2, 96.0f));
    h = (1.0f - u) * RCP((1.0f + s) * (1.0f + u));
}

// Wave tile: 32 elements. One mfma_f32_32x32x16_f16 per step: L0 gates(t) rows 0-15,
// L1 gates(t-1) rows 16-31. B = [x(t) k0-1 | h0 k2-5 | h1 k6-9 | 0]. Bias in C.
// h-exchange on VALU via permlane32_swap; x pre-packed f16 in wave-private LDS.
__global__ __launch_bounds__(256, 6) void lstm_mfma32(
    const float* __restrict__ x,
    const float* __restrict__ Wih0, const float* __restrict__ Whh0,
    const float* __restrict__ bih0, const float* __restrict__ bhh0,
    const float* __restrict__ Wih1, const float* __restrict__ Whh1,
    const float* __restrict__ bih1, const float* __restrict__ bhh1,
    const float* __restrict__ Wout, const float* __restrict__ bout,
    float* __restrict__ out, int B)
{
    __shared__ float2 wout_s[T_LEN*2];                  // [t][h]=(W[t*4+h],W[t*4+h+2])
    __shared__ __align__(8) unsigned xstage[4*32*T_LEN]; // packed f16 x, per wave
    const int tid = threadIdx.x;
    if (tid < T_LEN*2){
        const int t = tid >> 1, hh = tid & 1;
        wout_s[tid] = make_float2(Wout[t*4+hh], Wout[t*4+hh+2]);
    }
    __syncthreads();

    const int lane = tid & 63;
    const int e = lane & 31;          // element column
    const int h = lane >> 5;          // half: owns units {h, 2+h} per layer
    const int wslot = tid >> 6;
    const int wave = (blockIdx.x*256 + tid) >> 6;
    const int E0 = wave * 32;
    if (E0 >= B) return;

    unsigned* xr = xstage + wslot * (32*T_LEN);

    const float S1 = -1.4426950408889634f;
    const float S2 = -2.8853900817779268f;

    // ---- A fragment: lane supplies row mA=e, k=8h+0..7 ----
    const int qA = e >> 2, tA = e & 3;
    const float sA = (tA == 2) ? S2 : S1;
    uint4v au;
#pragma unroll
    for (int p = 0; p < 4; ++p){
        float vv[2];
#pragma unroll
        for (int z = 0; z < 2; ++z){
            const int k = 8*h + 2*p + z;
            float v = 0.f;
            if (qA < 4){                          // L0 rows: x(k0-1), h0(k2-5)
                const int r = tA*4 + qA;
                if (k < 2)      v = Wih0[r*2 + k];
                else if (k < 6) v = Whh0[r*4 + (k-2)];
            } else {                              // L1 rows: h0(k2-5), h1(k6-9)
                const int r = tA*4 + (qA-4);
                if (k >= 2 && k < 6)       v = Wih1[r*4 + (k-2)];
                else if (k >= 6 && k < 10) v = Whh1[r*4 + (k-6)];
            }
            vv[z] = v * sA;
        }
        au[p] = PKU(vv[0], vv[1]);
    }
    const fp16x8 Afrag = __builtin_bit_cast(fp16x8, au);

    // ---- bias as C operand (loop-invariant) ----
    f32x16 biasC;
#pragma unroll
    for (int r = 0; r < 16; ++r){
        const int m = (r&3) + 8*(r>>2) + 4*h;
        const int q = m >> 2, tg = m & 3;
        const float st = (tg == 2) ? S2 : S1;
        if (q < 4){ const int rr = tg*4 + q;      biasC[r] = (bih0[rr]+bhh0[rr])*st; }
        else      { const int rr = tg*4 + (q-4);  biasC[r] = (bih1[rr]+bhh1[rr])*st; }
    }

    // ---- stage x: 800 float4 -> 1600 packed-f16 u32 (wave-private, one-shot) ----
    const float* xg = x + (size_t)E0 * (T_LEN*2);
#pragma unroll
    for (int k = 0; k < 13; ++k){
        const int i = 64*k + lane;
        if (i < 800){
            const float4 v = *reinterpret_cast<const float4*>(xg + i*4);
            const int e_ = i/25, t0 = (i%25)*2;   // 4 floats = 2 steps, no straddle
            const unsigned lo = PKU(v.x, v.y);
            const unsigned hi = PKU(v.z, v.w);
            *reinterpret_cast<unsigned long long*>(&xr[e_*T_LEN + t0]) =
                ((unsigned long long)hi << 32) | lo;
        }
    }

    float c0l=0.f, c0h=0.f, c1l=0.f, c1h=0.f, acc=0.f;
    unsigned P0=0u, Q0=0u, P1=0u;   // P0=[pk_h0_01|both], Q0=[pk_h0_23|both], P1=[pk_h1_01|pk_h1_23]

    auto mainstep = [&](int t, unsigned ux){
        uint4v bu;
        bu[0] = h ? P1 : ux;     // half0: x(t); half1: h1 units 2,3 (k8-9)
        bu[1] = P0;              // half0: h0 units 0,1 (k2-3)
        bu[2] = Q0;              // half0: h0 units 2,3 (k4-5)
        bu[3] = P1;              // half0: h1 units 0,1 (k6-7)
        const f32x16 d = __builtin_amdgcn_mfma_f32_32x32x16_f16(
            Afrag, __builtin_bit_cast(fp16x8, bu), biasC, 0, 0, 0);
        float h0l,h0h,h1l,h1h;
        act(d[0], d[1], d[2], d[3],  c0l, h0l);
        act(d[4], d[5], d[6], d[7],  c0h, h0h);
        act(d[8], d[9], d[10],d[11], c1l, h1l);
        act(d[12],d[13],d[14],d[15], c1h, h1h);
        const float2 wo = wout_s[(t-1)*2 + h];
        acc = fmaf(h1l, wo.x, fmaf(h1h, wo.y, acc));
        // h0: 2 swaps + 1 pack -> pk01/pk23 on both halves
        float a0 = h0l, b0 = h0h;
        plswapf(a0, b0);                 // a0=[u0|u2], b0=[u1|u3]
        P0 = PKU(a0, b0);                // [pk01 | pk23]
        Q0 = P0;
        plswapu(P0, Q0);                 // P0=[pk01|pk01], Q0=[pk23|pk23]
        // h1: 1 swap + 1 pack -> consumers sit on matching halves
        float a1 = h1l, b1 = h1h;
        plswapf(a1, b1);
        P1 = PKU(a1, b1);                // [pk01 | pk23]
    };

    // ---- prologue t=0: L0 only ----
    {
        const unsigned ux = xr[e*T_LEN + 0];
        uint4v bu; bu[0] = h ? 0u : ux; bu[1]=0u; bu[2]=0u; bu[3]=0u;
        const f32x16 d = __builtin_amdgcn_mfma_f32_32x32x16_f16(
            Afrag, __builtin_bit_cast(fp16x8, bu), biasC, 0, 0, 0);
        float h0l, h0h;
        act(d[0],d[1],d[2],d[3], c0l, h0l);
        act(d[4],d[5],d[6],d[7], c0h, h0h);
        float a0 = h0l, b0 = h0h;
        plswapf(a0, b0);
        P0 = PKU(a0, b0);
        Q0 = P0;
        plswapu(P0, Q0);
        P1 = 0u;
    }

    // ---- main loop, x read pipelined one step ahead ----
    unsigned xc = xr[e*T_LEN + 1];
    for (int t = 1; t < T_LEN; ++t){
        const unsigned xn = xr[e*T_LEN + ((t < T_LEN-1) ? t+1 : t)];
        mainstep(t, xc);
        xc = xn;
    }

    // ---- epilogue: L1 at t=49 ----
    {
        uint4v bu;
        bu[0] = h ? P1 : 0u;
        bu[1] = P0; bu[2] = Q0; bu[3] = P1;
        const f32x16 d = __builtin_amdgcn_mfma_f32_32x32x16_f16(
            Afrag, __builtin_bit_cast(fp16x8, bu), biasC, 0, 0, 0);
        float h1l, h1h;
        act(d[8], d[9], d[10],d[11], c1l, h1l);
        act(d[12],d[13],d[14],d[15], c1h, h1h);
        const float2 wo = wout_s[49*2 + h];
        acc = fmaf(h1l, wo.x, fmaf(h1h, wo.y, acc));
    }

    acc += __shfl_xor(acc, 32, 64);
    if (h == 0){
        const float z = acc + bout[0];
        out[E0 + e] = RCP(1.0f + EXP2(z * S1));   // sigmoid
    }
}

extern "C" void kernel_launch(void* const* d_in, const int* in_sizes, int n_in,
                              void* d_out, int out_size, void* d_ws, size_t ws_size,
                              hipStream_t stream)
{
    const float* x    = (const float*)d_in[0];
    const float* Wih0 = (const float*)d_in[1];
    const float* Whh0 = (const float*)d_in[2];
    const float* bih0 = (const float*)d_in[3];
    const float* bhh0 = (const float*)d_in[4];
    const float* Wih1 = (const float*)d_in[5];
    const float* Whh1 = (const float*)d_in[6];
    const float* bih1 = (const float*)d_in[7];
    const float* bhh1 = (const float*)d_in[8];
    const float* Wout = (const float*)d_in[9];
    const float* bout = (const float*)d_in[10];
    float* out = (float*)d_out;

    const int B = in_sizes[0] / (T_LEN*2);
    const int waves = (B + 31) / 32;
    const int blocks = (waves + 3) / 4;       // 4 waves per 256-thread block
    lstm_mfma32<<<blocks, 256, 0, stream>>>(x, Wih0, Whh0, bih0, bhh0,
                                            Wih1, Whh1, bih1, bhh1,
                                            Wout, bout, out, B);
}